// Round 1
// baseline (526.867 us; speedup 1.0000x reference)
//
#include <hip/hip_runtime.h>
#include <hip/hip_bf16.h>
#include <math.h>

// Problem constants (B, Cin, Cout, N, modes) = (16, 128, 128, 8192, 64)
#define NB    16
#define NCIN  128
#define NCOUT 128
#define NN    8192
#define NMOD  64

// -------- Stage 1: forward DFT, first 64 modes of each length-8192 row -----
// grid: 2048 blocks (one per b*Cin+i row), 256 threads.
// thread (k = tid&63, g = tid>>6) accumulates mode k over quarter g.
__global__ __launch_bounds__(256) void k_dft(const float* __restrict__ x,
                                             float* __restrict__ Xf) {
    const int row = blockIdx.x;              // 0..2047
    const float* xr = x + (size_t)row * NN;
    __shared__ __align__(16) float sx[NN];   // 32 KB
    __shared__ float red[512];
    for (int idx = threadIdx.x; idx < NN / 4; idx += 256)
        ((float4*)sx)[idx] = ((const float4*)xr)[idx];
    __syncthreads();

    const int k = threadIdx.x & 63;
    const int g = threadIdx.x >> 6;          // 0..3
    const float step = -7.66990393943e-4f;   // -2*pi/8192
    float c1, s1;
    __sincosf(step * (float)k, &s1, &c1);    // per-sample rotation e^{-2pi i k/N}

    float accr = 0.f, acci = 0.f;
    for (int seg = 0; seg < 16; ++seg) {
        int n0 = g * 2048 + seg * 128;
        int ph = (k * n0) & (NN - 1);
        float c, s;
        __sincosf(step * (float)ph, &s, &c); // resync: kills recurrence drift
        #pragma unroll 8
        for (int t = 0; t < 128; ++t) {
            float xv = sx[n0 + t];           // broadcast within wave (same n)
            accr = fmaf(xv, c, accr);
            acci = fmaf(xv, s, acci);
            float c2 = c * c1 - s * s1;      // rotate twiddle
            s = c * s1 + s * c1;
            c = c2;
        }
    }
    red[threadIdx.x] = accr;
    red[256 + threadIdx.x] = acci;
    __syncthreads();
    if (threadIdx.x < 64) {
        int tk = threadIdx.x;
        float sr = red[tk] + red[tk + 64] + red[tk + 128] + red[tk + 192];
        float si = red[256 + tk] + red[256 + tk + 64] + red[256 + tk + 128] + red[256 + tk + 192];
        Xf[(size_t)row * 128 + tk * 2]     = sr;   // [row][k][{re,im}]
        Xf[(size_t)row * 128 + tk * 2 + 1] = si;
    }
}

// -------- Stage 2: complex channel mix + irfft scaling --------------------
// Ym'[b][o][k] = scale_k * sum_i Xf[b][i][k] * (wr + j wi)[i][o][k]
// scale: k==0 -> 1/N (and Im:=0, matching c2r bin-0 convention); else 2/N.
__global__ __launch_bounds__(256) void k_mix(const float* __restrict__ Xf,
                                             const float* __restrict__ wsp,
                                             float* __restrict__ Ym) {
    int t = blockIdx.x * 256 + threadIdx.x;  // 16*128*64 = 131072 threads
    int k = t & 63;
    int o = (t >> 6) & 127;
    int b = t >> 13;
    const float* xf = Xf + (size_t)b * (NCIN * 128) + k * 2;   // + i*128
    const float* w  = wsp + (size_t)o * 128 + k * 2;           // + i*16384
    float sr = 0.f, si = 0.f;
    #pragma unroll 4
    for (int i = 0; i < NCIN; ++i) {
        float xr = xf[i * 128], xi = xf[i * 128 + 1];
        float wr = w[(size_t)i * 16384], wi = w[(size_t)i * 16384 + 1];
        sr += xr * wr - xi * wi;
        si += xr * wi + xi * wr;
    }
    if (k == 0) { sr *= (1.f / NN); si = 0.f; }
    else        { sr *= (2.f / NN); si *= (2.f / NN); }
    Ym[(size_t)t * 2]     = sr;   // [b][o][k][{re,im}]
    Ym[(size_t)t * 2 + 1] = si;
}

// -------- Stage 3: inverse synthesis + 1x1 conv + bias + exact GELU -------
// grid: 16 b * 64 n-tiles = 1024 blocks, 256 threads.
// thread = (n_local = tid&127, o_half = tid>>7), owns 64 o-outputs at one n.
// LDS (32 KB) reused: Ym k-halves (phase A), W i-halves (phase B).
__global__ __launch_bounds__(256) void k_fuse(const float* __restrict__ x,
                                              const float* __restrict__ Wc,
                                              const float* __restrict__ bias,
                                              const float* __restrict__ Ym,
                                              float* __restrict__ out) {
    const int b     = blockIdx.x >> 6;
    const int tile  = blockIdx.x & 63;
    const int nl    = threadIdx.x & 127;
    const int oh    = threadIdx.x >> 7;
    const int n     = tile * 128 + nl;
    const int obase = oh * 64;
    __shared__ __align__(16) float s0[8192];   // 32 KB
    float acc[64];
    #pragma unroll
    for (int j = 0; j < 64; ++j) acc[j] = 0.f;

    // Phase A: x1[n] = sum_k Yr'[k] cos(2pi k n/N) - Yi'[k] sin(2pi k n/N)
    for (int kh = 0; kh < 2; ++kh) {
        __syncthreads();
        for (int idx = threadIdx.x; idx < 8192; idx += 256) {
            int o = idx >> 6, lo = idx & 63;
            s0[idx] = Ym[(size_t)b * 16384 + o * 128 + kh * 64 + lo];
        }
        __syncthreads();
        for (int kk = 0; kk < 32; ++kk) {
            int k = kh * 32 + kk;
            int ph = (k * n) & (NN - 1);
            float sn, cn;
            __sincosf((float)ph * 7.66990393943e-4f, &sn, &cn);
            #pragma unroll
            for (int j = 0; j < 64; ++j) {
                float2 y = *(const float2*)&s0[(obase + j) * 64 + kk * 2];
                acc[j] += y.x * cn - y.y * sn;   // LDS broadcast across n-lanes
            }
        }
    }

    // Phase B: += sum_i W[o][i] * x[b][i][n]
    for (int ih = 0; ih < 2; ++ih) {
        __syncthreads();
        for (int idx = threadIdx.x; idx < 8192; idx += 256) {
            int o = idx >> 6, ii = idx & 63;
            s0[idx] = Wc[o * 128 + ih * 64 + ii];
        }
        __syncthreads();
        const float* xb = x + ((size_t)b * NCIN + ih * 64) * NN + n;
        for (int c = 0; c < 64; c += 4) {
            float x0 = xb[(size_t)(c + 0) * NN];
            float x1 = xb[(size_t)(c + 1) * NN];
            float x2 = xb[(size_t)(c + 2) * NN];
            float x3 = xb[(size_t)(c + 3) * NN];
            #pragma unroll
            for (int j = 0; j < 64; ++j) {
                float4 w = *(const float4*)&s0[(obase + j) * 64 + c];
                acc[j] = fmaf(x0, w.x, fmaf(x1, w.y, fmaf(x2, w.z, fmaf(x3, w.w, acc[j]))));
            }
        }
    }

    // Epilogue: bias + exact GELU, coalesced store
    float* ob = out + ((size_t)b * NCOUT + obase) * NN + n;
    #pragma unroll
    for (int j = 0; j < 64; ++j) {
        float v = acc[j] + bias[obase + j];
        ob[(size_t)j * NN] = 0.5f * v * (1.f + erff(v * 0.70710678118f));
    }
}

extern "C" void kernel_launch(void* const* d_in, const int* in_sizes, int n_in,
                              void* d_out, int out_size, void* d_ws, size_t ws_size,
                              hipStream_t stream) {
    const float* x    = (const float*)d_in[0];  // [16][128][8192]
    const float* wsp  = (const float*)d_in[1];  // [128][128][64][2]
    const float* wc   = (const float*)d_in[2];  // [128][128]
    const float* bc   = (const float*)d_in[3];  // [128]
    float* out = (float*)d_out;                 // [16][128][8192]

    float* Xf = (float*)d_ws;                   // 2048*64*2 floats = 1 MB
    float* Ym = Xf + (size_t)2048 * 128;        // 16*128*64*2 floats = 1 MB

    k_dft <<<NB * NCIN, 256, 0, stream>>>(x, Xf);
    k_mix <<<(NB * NCOUT * NMOD) / 256, 256, 0, stream>>>(Xf, wsp, Ym);
    k_fuse<<<NB * (NN / 128), 256, 0, stream>>>(x, wc, bc, Ym, out);
}

// Round 2
// 224.664 us; speedup vs baseline: 2.3451x; 2.3451x over previous
//
#include <hip/hip_runtime.h>
#include <hip/hip_bf16.h>
#include <math.h>

// (B, Cin, Cout, N, modes) = (16, 128, 128, 8192, 64)
#define NB    16
#define NCIN  128
#define NCOUT 128
#define NN    8192
#define NMOD  64

typedef short bf16x8 __attribute__((ext_vector_type(8)));   // 8 bf16 = 4 VGPRs
typedef float f32x4  __attribute__((ext_vector_type(4)));   // MFMA acc

#define MFMA16(a, b, c) __builtin_amdgcn_mfma_f32_16x16x32_bf16((a), (b), (c), 0, 0, 0)

__device__ inline unsigned short f2bf_rne(float f) {        // round-to-nearest-even
    unsigned u = __float_as_uint(f);
    u += 0x7FFF + ((u >> 16) & 1);
    return (unsigned short)(u >> 16);
}
__device__ inline short f2bf_trunc(float f) {               // cheap truncation (hot path)
    return (short)(__float_as_uint(f) >> 16);
}

// ---- prep: trig tables (both layouts) + bf16 conv weight --------------------
// T [128][8192]: T[2k][n]=cos(2pi k n/N), T[2k+1][n]=-sin(2pi k n/N)   (fwd-DFT B-op)
// Tt[8192][128]: Tt[n][m]=T[m][n]                                      (synthesis B-op)
__global__ __launch_bounds__(256) void k_prep(const float* __restrict__ wc,
                                              unsigned short* __restrict__ T,
                                              unsigned short* __restrict__ Tt,
                                              unsigned short* __restrict__ Wcb) {
    const float C = 7.66990393943e-4f; // 2*pi/8192
    if (blockIdx.x < 16) {                         // region A: T rows
        int a = blockIdx.x * 256 + threadIdx.x;    // 4096 threads
        int k = a >> 6, n0 = (a & 63) * 128;
        for (int j8 = 0; j8 < 16; ++j8) {
            short c8[8], s8[8];
            #pragma unroll
            for (int j = 0; j < 8; ++j) {
                int n = n0 + j8 * 8 + j;
                int ph = (k * n) & (NN - 1);
                float sn, cs; __sincosf((float)ph * C, &sn, &cs);
                c8[j] = (short)f2bf_rne(cs);
                s8[j] = (short)f2bf_rne(-sn);
            }
            *(bf16x8*)(T + (size_t)(2 * k) * NN + n0 + j8 * 8)     = *(bf16x8*)c8;
            *(bf16x8*)(T + (size_t)(2 * k + 1) * NN + n0 + j8 * 8) = *(bf16x8*)s8;
        }
    } else if (blockIdx.x < 48) {                  // region B: Tt rows
        int n = (blockIdx.x - 16) * 256 + threadIdx.x;   // 8192 threads
        for (int k4 = 0; k4 < 16; ++k4) {
            short buf[8];
            #pragma unroll
            for (int j = 0; j < 4; ++j) {
                int k = k4 * 4 + j;
                int ph = (n * k) & (NN - 1);
                float sn, cs; __sincosf((float)ph * C, &sn, &cs);
                buf[2 * j]     = (short)f2bf_rne(cs);
                buf[2 * j + 1] = (short)f2bf_rne(-sn);
            }
            *(bf16x8*)(Tt + (size_t)n * 128 + k4 * 8) = *(bf16x8*)buf;
        }
    } else {                                       // region C: Wc -> bf16
        int j = (blockIdx.x - 48) * 256 + threadIdx.x;
        if (j < NCOUT * NCIN) Wcb[j] = f2bf_rne(wc[j]);
    }
}

// ---- GEMM1: Xf-partials = x[2048][8192] * T^T, K-split 16 -------------------
// block: 64 M-rows x 128 cols, K-chunk 512. 4 waves; wave w: cols [w*32,w*32+32).
__global__ __launch_bounds__(256) void k_dftmm(const float* __restrict__ x,
                                               const unsigned short* __restrict__ T,
                                               float* __restrict__ Cpart) {
    const int mt = blockIdx.x & 31, sp = blockIdx.x >> 5;
    const int w = threadIdx.x >> 6, l = threadIdx.x & 63;
    const int l15 = l & 15, q = l >> 4;
    const int colbase = w * 32;
    f32x4 acc[4][2] = {};
    for (int kt = 0; kt < 16; ++kt) {
        const int kb = sp * 512 + kt * 32;
        bf16x8 a[4], bb[2];
        #pragma unroll
        for (int mf = 0; mf < 4; ++mf) {
            const float* ap = x + (size_t)(mt * 64 + mf * 16 + l15) * NN + kb + q * 8;
            float4 f0 = *(const float4*)ap;
            float4 f1 = *(const float4*)(ap + 4);
            short t8[8] = { f2bf_trunc(f0.x), f2bf_trunc(f0.y), f2bf_trunc(f0.z), f2bf_trunc(f0.w),
                            f2bf_trunc(f1.x), f2bf_trunc(f1.y), f2bf_trunc(f1.z), f2bf_trunc(f1.w) };
            a[mf] = *(bf16x8*)t8;
        }
        #pragma unroll
        for (int nf = 0; nf < 2; ++nf)
            bb[nf] = *(const bf16x8*)(T + (size_t)(colbase + nf * 16 + l15) * NN + kb + q * 8);
        #pragma unroll
        for (int mf = 0; mf < 4; ++mf) {
            acc[mf][0] = MFMA16(a[mf], bb[0], acc[mf][0]);
            acc[mf][1] = MFMA16(a[mf], bb[1], acc[mf][1]);
        }
    }
    #pragma unroll
    for (int mf = 0; mf < 4; ++mf)
        #pragma unroll
        for (int nf = 0; nf < 2; ++nf)
            #pragma unroll
            for (int r = 0; r < 4; ++r) {
                int row = mt * 64 + mf * 16 + q * 4 + r;
                int col = colbase + nf * 16 + l15;
                Cpart[((size_t)sp * 2048 + row) * 128 + col] = acc[mf][nf][r];
            }
}

// ---- reduce 16 K-split partials -> Xf[2048][128] ----------------------------
__global__ __launch_bounds__(256) void k_reduce(const float* __restrict__ Cpart,
                                                float* __restrict__ Xf) {
    int t = blockIdx.x * 256 + threadIdx.x;   // 262144
    float s = 0.f;
    #pragma unroll
    for (int sp = 0; sp < 16; ++sp) s += Cpart[(size_t)sp * 262144 + t];
    Xf[t] = s;
}

// ---- mix: complex channel mix + irfft scale, emit bf16 Aspec ----------------
__global__ __launch_bounds__(256) void k_mix(const float* __restrict__ Xf,
                                             const float* __restrict__ wsp,
                                             unsigned short* __restrict__ Aspec) {
    int t = blockIdx.x * 256 + threadIdx.x;  // 131072
    int k = t & 63, o = (t >> 6) & 127, b = t >> 13;
    const float* xf = Xf + (size_t)b * (NCIN * 128) + k * 2;
    const float* w  = wsp + (size_t)o * 128 + k * 2;
    float sr = 0.f, si = 0.f;
    #pragma unroll 4
    for (int i = 0; i < NCIN; ++i) {
        float xr = xf[i * 128], xi = xf[i * 128 + 1];
        float wr = w[(size_t)i * 16384], wi = w[(size_t)i * 16384 + 1];
        sr += xr * wr - xi * wi;
        si += xr * wi + xi * wr;
    }
    if (k == 0) { sr *= (1.f / NN); si = 0.f; }
    else        { sr *= (2.f / NN); si *= (2.f / NN); }
    unsigned short pair[2] = { f2bf_rne(sr), f2bf_rne(si) };
    *(unsigned int*)(Aspec + ((size_t)(b * 128 + o)) * 128 + 2 * k) = *(unsigned int*)pair;
}

// ---- GEMM3: out[b][o][n] = [Aspec_b | Wcb] x [Tt^T ; x_b] + bias, GELU ------
// grid: 16 b x 64 n-tiles(128). 4 waves; wave w: n-sub [w*32,+32), full o=128.
__global__ __launch_bounds__(256) void k_out(const float* __restrict__ x,
                                             const unsigned short* __restrict__ Tt,
                                             const unsigned short* __restrict__ Aspec,
                                             const unsigned short* __restrict__ Wcb,
                                             const float* __restrict__ bias,
                                             float* __restrict__ out) {
    const int b = blockIdx.x >> 6, nt = blockIdx.x & 63;
    const int w = threadIdx.x >> 6, l = threadIdx.x & 63;
    const int l15 = l & 15, q = l >> 4;
    const int nbase = nt * 128 + w * 32;
    f32x4 acc[8][2] = {};
    for (int kt = 0; kt < 8; ++kt) {
        bf16x8 bb[2];
        if (kt < 4) {                                       // spectral half: B from Tt
            #pragma unroll
            for (int nf = 0; nf < 2; ++nf) {
                int n = nbase + nf * 16 + l15;
                bb[nf] = *(const bf16x8*)(Tt + (size_t)n * 128 + kt * 32 + q * 8);
            }
        } else {                                            // conv half: B from fp32 x
            int i0 = (kt - 4) * 32 + q * 8;
            #pragma unroll
            for (int nf = 0; nf < 2; ++nf) {
                int n = nbase + nf * 16 + l15;
                const float* xp = x + ((size_t)(b * 128 + i0)) * NN + n;
                short t8[8];
                #pragma unroll
                for (int j = 0; j < 8; ++j) t8[j] = f2bf_trunc(xp[(size_t)j * NN]);
                bb[nf] = *(bf16x8*)t8;
            }
        }
        const unsigned short* Ap = (kt < 4)
            ? (Aspec + (size_t)b * 128 * 128 + kt * 32 + q * 8)
            : (Wcb + (kt - 4) * 32 + q * 8);
        #pragma unroll
        for (int mf = 0; mf < 8; ++mf) {
            bf16x8 a = *(const bf16x8*)(Ap + (size_t)(mf * 16 + l15) * 128);
            acc[mf][0] = MFMA16(a, bb[0], acc[mf][0]);
            acc[mf][1] = MFMA16(a, bb[1], acc[mf][1]);
        }
    }
    // epilogue: bias + tanh-approx GELU (max dev 3e-3 << 6.3e-2 budget)
    #pragma unroll
    for (int mf = 0; mf < 8; ++mf)
        #pragma unroll
        for (int nf = 0; nf < 2; ++nf)
            #pragma unroll
            for (int r = 0; r < 4; ++r) {
                int o = mf * 16 + q * 4 + r;
                int n = nbase + nf * 16 + l15;
                float v = acc[mf][nf][r] + bias[o];
                float u = v * v;
                float p = v * fmaf(0.0713548162f, u, 1.5957691216f);   // 2s(v+0.044715v^3)
                float e = __expf(-p);
                float g = v * __builtin_amdgcn_rcpf(1.f + e);          // v*sigmoid(p)
                out[((size_t)(b * 128 + o)) * NN + n] = g;
            }
}

extern "C" void kernel_launch(void* const* d_in, const int* in_sizes, int n_in,
                              void* d_out, int out_size, void* d_ws, size_t ws_size,
                              hipStream_t stream) {
    const float* x    = (const float*)d_in[0];  // [16][128][8192]
    const float* wsp  = (const float*)d_in[1];  // [128][128][64][2]
    const float* wc   = (const float*)d_in[2];  // [128][128]
    const float* bc   = (const float*)d_in[3];  // [128]
    float* out = (float*)d_out;

    unsigned short* T   = (unsigned short*)d_ws;            // 2 MB
    unsigned short* Tt  = T + (size_t)1048576;              // 2 MB
    unsigned short* Wcb = Tt + (size_t)1048576;             // 32 KB
    unsigned short* Asp = Wcb + 16384;                      // 512 KB
    float* Cpart = (float*)(Asp + 262144);                  // 16 MB
    float* Xf    = Cpart + (size_t)16 * 262144;             // 1 MB   (total ~21.5 MB)

    k_prep  <<<112,  256, 0, stream>>>(wc, T, Tt, Wcb);
    k_dftmm <<<512,  256, 0, stream>>>(x, T, Cpart);
    k_reduce<<<1024, 256, 0, stream>>>(Cpart, Xf);
    k_mix   <<<512,  256, 0, stream>>>(Xf, wsp, Asp);
    k_out   <<<1024, 256, 0, stream>>>(x, Tt, Asp, Wcb, bc, out);
}

// Round 3
// 221.290 us; speedup vs baseline: 2.3809x; 1.0152x over previous
//
#include <hip/hip_runtime.h>
#include <hip/hip_bf16.h>
#include <math.h>

// (B, Cin, Cout, N, modes) = (16, 128, 128, 8192, 64)
#define NB    16
#define NCIN  128
#define NCOUT 128
#define NN    8192
#define NMOD  64

typedef short bf16x8 __attribute__((ext_vector_type(8)));   // 8 bf16 = 4 VGPRs
typedef float f32x4  __attribute__((ext_vector_type(4)));   // MFMA acc

#define MFMA16(a, b, c) __builtin_amdgcn_mfma_f32_16x16x32_bf16((a), (b), (c), 0, 0, 0)

__device__ inline unsigned short f2bf_rne(float f) {        // round-to-nearest-even
    unsigned u = __float_as_uint(f);
    u += 0x7FFF + ((u >> 16) & 1);
    return (unsigned short)(u >> 16);
}
__device__ inline short f2bf_trunc(float f) {               // cheap truncation (hot path)
    return (short)(__float_as_uint(f) >> 16);
}

// ---- prep: trig tables, bf16 conv weight, packed spectral weights -----------
// T  [128][8192]: T[2k][n]=cos, T[2k+1][n]=-sin            (fwd-DFT B-op)
// Tt [8192][128]: Tt[n][m]=T[m][n]                         (synthesis B-op)
// Wpk[k][h][o][kk=256] bf16: h=0 re-mix, h=1 im-mix; scale 2/N (1/N, im=0 at k=0)
__global__ __launch_bounds__(256) void k_prep(const float* __restrict__ wc,
                                              const float* __restrict__ wsp,
                                              unsigned short* __restrict__ T,
                                              unsigned short* __restrict__ Tt,
                                              unsigned short* __restrict__ Wcb,
                                              unsigned short* __restrict__ Wpk) {
    const float C = 7.66990393943e-4f; // 2*pi/8192
    if (blockIdx.x < 16) {                         // region A: T rows
        int a = blockIdx.x * 256 + threadIdx.x;
        int k = a >> 6, n0 = (a & 63) * 128;
        for (int j8 = 0; j8 < 16; ++j8) {
            short c8[8], s8[8];
            #pragma unroll
            for (int j = 0; j < 8; ++j) {
                int n = n0 + j8 * 8 + j;
                int ph = (k * n) & (NN - 1);
                float sn, cs; __sincosf((float)ph * C, &sn, &cs);
                c8[j] = (short)f2bf_rne(cs);
                s8[j] = (short)f2bf_rne(-sn);
            }
            *(bf16x8*)(T + (size_t)(2 * k) * NN + n0 + j8 * 8)     = *(bf16x8*)c8;
            *(bf16x8*)(T + (size_t)(2 * k + 1) * NN + n0 + j8 * 8) = *(bf16x8*)s8;
        }
    } else if (blockIdx.x < 48) {                  // region B: Tt rows
        int n = (blockIdx.x - 16) * 256 + threadIdx.x;
        for (int k4 = 0; k4 < 16; ++k4) {
            short buf[8];
            #pragma unroll
            for (int j = 0; j < 4; ++j) {
                int k = k4 * 4 + j;
                int ph = (n * k) & (NN - 1);
                float sn, cs; __sincosf((float)ph * C, &sn, &cs);
                buf[2 * j]     = (short)f2bf_rne(cs);
                buf[2 * j + 1] = (short)f2bf_rne(-sn);
            }
            *(bf16x8*)(Tt + (size_t)n * 128 + k4 * 8) = *(bf16x8*)buf;
        }
    } else if (blockIdx.x < 112) {                 // region C: Wc -> bf16
        int j = (blockIdx.x - 48) * 256 + threadIdx.x;
        if (j < NCOUT * NCIN) Wcb[j] = f2bf_rne(wc[j]);
    } else {                                       // region D: pack Wpk
        int g2 = (blockIdx.x - 112) * 256 + threadIdx.x;   // 0..32767
        int k  = g2 & 63;
        int o  = (g2 >> 6) & 127;
        int ch = g2 >> 13;                                  // 0..3
        const float s = (k == 0) ? (1.f / NN) : (2.f / NN);
        const float2* wp = (const float2*)wsp;              // [(i*128+o)*64 + k]
        unsigned short* wre = Wpk + ((size_t)(k * 2 + 0) * 128 + o) * 256;
        unsigned short* wim = Wpk + ((size_t)(k * 2 + 1) * 128 + o) * 256;
        for (int c = ch * 8; c < ch * 8 + 8; ++c) {
            int i0 = 4 * c;
            short re8[8], im8[8];
            #pragma unroll
            for (int t2 = 0; t2 < 4; ++t2) {
                float2 wv = wp[((size_t)(i0 + t2) * 128 + o) * 64 + k];  // lanes: k-contig
                float wr = s * wv.x, wi = s * wv.y;
                re8[2 * t2]     = (short)f2bf_rne(wr);
                re8[2 * t2 + 1] = (short)f2bf_rne(-wi);
                im8[2 * t2]     = (k == 0) ? (short)0 : (short)f2bf_rne(wi);
                im8[2 * t2 + 1] = (k == 0) ? (short)0 : (short)f2bf_rne(wr);
            }
            *(bf16x8*)(wre + c * 8) = *(bf16x8*)re8;   // per-lane sequential -> L2 merges
            *(bf16x8*)(wim + c * 8) = *(bf16x8*)im8;
        }
    }
}

// ---- GEMM1: Cpart_t[sp][col][row] = (x * T^T) K-split partials --------------
__global__ __launch_bounds__(256) void k_dftmm(const float* __restrict__ x,
                                               const unsigned short* __restrict__ T,
                                               float* __restrict__ Cpart) {
    const int mt = blockIdx.x & 31, sp = blockIdx.x >> 5;
    const int w = threadIdx.x >> 6, l = threadIdx.x & 63;
    const int l15 = l & 15, q = l >> 4;
    const int colbase = w * 32;
    f32x4 acc[4][2] = {};
    for (int kt = 0; kt < 16; ++kt) {
        const int kb = sp * 512 + kt * 32;
        bf16x8 a[4], bb[2];
        #pragma unroll
        for (int mf = 0; mf < 4; ++mf) {
            const float* ap = x + (size_t)(mt * 64 + mf * 16 + l15) * NN + kb + q * 8;
            float4 f0 = *(const float4*)ap;
            float4 f1 = *(const float4*)(ap + 4);
            short t8[8] = { f2bf_trunc(f0.x), f2bf_trunc(f0.y), f2bf_trunc(f0.z), f2bf_trunc(f0.w),
                            f2bf_trunc(f1.x), f2bf_trunc(f1.y), f2bf_trunc(f1.z), f2bf_trunc(f1.w) };
            a[mf] = *(bf16x8*)t8;
        }
        #pragma unroll
        for (int nf = 0; nf < 2; ++nf)
            bb[nf] = *(const bf16x8*)(T + (size_t)(colbase + nf * 16 + l15) * NN + kb + q * 8);
        #pragma unroll
        for (int mf = 0; mf < 4; ++mf) {
            acc[mf][0] = MFMA16(a[mf], bb[0], acc[mf][0]);
            acc[mf][1] = MFMA16(a[mf], bb[1], acc[mf][1]);
        }
    }
    #pragma unroll
    for (int mf = 0; mf < 4; ++mf)
        #pragma unroll
        for (int nf = 0; nf < 2; ++nf) {
            int col  = colbase + nf * 16 + l15;
            int row0 = mt * 64 + mf * 16 + q * 4;
            *(f32x4*)(Cpart + (size_t)sp * 262144 + (size_t)col * 2048 + row0) = acc[mf][nf];
        }
}

// ---- reduce 16 K-split partials -> Xf_t[col=2k+p][row=b*128+i] --------------
__global__ __launch_bounds__(256) void k_reduce(const float* __restrict__ Cpart,
                                                float* __restrict__ Xf) {
    int t = blockIdx.x * 256 + threadIdx.x;   // 262144
    float s = 0.f;
    #pragma unroll
    for (int sp = 0; sp < 16; ++sp) s += Cpart[(size_t)sp * 262144 + t];
    Xf[t] = s;
}

// ---- mix: MFMA complex channel mix -> Aspec[b][o][kk=2k+p] bf16 -------------
// grid 256 blocks x 1 wave: block = (k, o-quarter of 32). C[16 b][32 o], K=256.
__global__ __launch_bounds__(64) void k_mixmm(const float* __restrict__ Xf,
                                              const unsigned short* __restrict__ Wpk,
                                              unsigned short* __restrict__ Aspec) {
    const int k = blockIdx.x >> 2, oq = blockIdx.x & 3;
    const int l = threadIdx.x, l15 = l & 15, q = l >> 4;
    f32x4 ar[2] = {}, ai[2] = {};
    const float* xr = Xf + (size_t)(2 * k) * 2048 + l15 * 128;   // b = l15
    const float* xi = xr + 2048;
    #pragma unroll
    for (int kt = 0; kt < 8; ++kt) {
        int i0 = kt * 16 + q * 4;
        float4 r4 = *(const float4*)(xr + i0);
        float4 i4 = *(const float4*)(xi + i0);
        short a8[8] = { (short)f2bf_rne(r4.x), (short)f2bf_rne(i4.x),
                        (short)f2bf_rne(r4.y), (short)f2bf_rne(i4.y),
                        (short)f2bf_rne(r4.z), (short)f2bf_rne(i4.z),
                        (short)f2bf_rne(r4.w), (short)f2bf_rne(i4.w) };
        bf16x8 a = *(bf16x8*)a8;
        #pragma unroll
        for (int nf = 0; nf < 2; ++nf) {
            int o = oq * 32 + nf * 16 + l15;
            const unsigned short* wb = Wpk + ((size_t)(k * 2) * 128 + o) * 256 + kt * 32 + q * 8;
            bf16x8 bre = *(const bf16x8*)wb;
            bf16x8 bim = *(const bf16x8*)(wb + 32768);   // h-stride 128*256
            ar[nf] = MFMA16(a, bre, ar[nf]);
            ai[nf] = MFMA16(a, bim, ai[nf]);
        }
    }
    #pragma unroll
    for (int nf = 0; nf < 2; ++nf) {
        int o = oq * 32 + nf * 16 + l15;
        #pragma unroll
        for (int r = 0; r < 4; ++r) {
            int b = q * 4 + r;
            unsigned v = (unsigned)f2bf_rne(ar[nf][r]) | ((unsigned)f2bf_rne(ai[nf][r]) << 16);
            *(unsigned*)(Aspec + ((size_t)b * 128 + o) * 128 + 2 * k) = v;
        }
    }
}

// ---- GEMM3: out = [Aspec_b | Wcb] x [Tt^T ; x_b] + bias, GELU ---------------
// grid 16 b x 64 n-tiles. Conv-half B staged in LDS (bf16, XOR-swizzled).
__global__ __launch_bounds__(256) void k_out(const float* __restrict__ x,
                                             const unsigned short* __restrict__ Tt,
                                             const unsigned short* __restrict__ Aspec,
                                             const unsigned short* __restrict__ Wcb,
                                             const float* __restrict__ bias,
                                             float* __restrict__ out) {
    const int b = blockIdx.x >> 6, nt = blockIdx.x & 63;
    const int w = threadIdx.x >> 6, l = threadIdx.x & 63;
    const int l15 = l & 15, q = l >> 4;
    __shared__ short xs[16384];   // 32 KB: logical [n=128][i=128], chunk-swizzled

    // ---- stage x-tile: fp32 coalesced reads -> bf16 pairs, transposed writes
    const float* xb = x + (size_t)b * 128 * NN + nt * 128;
    #pragma unroll
    for (int it = 0; it < 8; ++it) {
        int unit = it * 256 + threadIdx.x;       // 2048 units
        int ipair = unit >> 5, nq = unit & 31;
        int i0 = ipair * 2;
        const float* p0 = xb + (size_t)i0 * NN + nq * 4;
        float4 r0 = *(const float4*)p0;
        float4 r1 = *(const float4*)(p0 + NN);
        float a0[4] = { r0.x, r0.y, r0.z, r0.w };
        float a1[4] = { r1.x, r1.y, r1.z, r1.w };
        #pragma unroll
        for (int j = 0; j < 4; ++j) {
            int n = nq * 4 + j;
            unsigned v = (unsigned)(unsigned short)f2bf_trunc(a0[j])
                       | ((unsigned)(unsigned short)f2bf_trunc(a1[j]) << 16);
            int addr = n * 128 + (((i0 >> 3) ^ (n & 15)) * 8) + (i0 & 7);
            *(unsigned*)&xs[addr] = v;
        }
    }

    f32x4 acc[8][2] = {};
    // ---- spectral half first (no LDS dependency -> staging drains for free)
    #pragma unroll
    for (int kt = 0; kt < 4; ++kt) {
        bf16x8 bb[2];
        #pragma unroll
        for (int nf = 0; nf < 2; ++nf) {
            int n = nt * 128 + w * 32 + nf * 16 + l15;
            bb[nf] = *(const bf16x8*)(Tt + (size_t)n * 128 + kt * 32 + q * 8);
        }
        const unsigned short* Ap = Aspec + (size_t)b * 16384 + kt * 32 + q * 8;
        #pragma unroll
        for (int mf = 0; mf < 8; ++mf) {
            bf16x8 a = *(const bf16x8*)(Ap + (size_t)(mf * 16 + l15) * 128);
            acc[mf][0] = MFMA16(a, bb[0], acc[mf][0]);
            acc[mf][1] = MFMA16(a, bb[1], acc[mf][1]);
        }
    }
    __syncthreads();
    // ---- conv half: B from LDS (ds_read_b128, swizzle-matched)
    #pragma unroll
    for (int kt = 0; kt < 4; ++kt) {
        bf16x8 bb[2];
        #pragma unroll
        for (int nf = 0; nf < 2; ++nf) {
            int nl = w * 32 + nf * 16 + l15;
            int c  = kt * 4 + q;
            bb[nf] = *(const bf16x8*)&xs[nl * 128 + ((c ^ (nl & 15)) * 8)];
        }
        const unsigned short* Ap = Wcb + kt * 32 + q * 8;
        #pragma unroll
        for (int mf = 0; mf < 8; ++mf) {
            bf16x8 a = *(const bf16x8*)(Ap + (size_t)(mf * 16 + l15) * 128);
            acc[mf][0] = MFMA16(a, bb[0], acc[mf][0]);
            acc[mf][1] = MFMA16(a, bb[1], acc[mf][1]);
        }
    }
    // ---- epilogue: bias + fast GELU
    #pragma unroll
    for (int mf = 0; mf < 8; ++mf)
        #pragma unroll
        for (int nf = 0; nf < 2; ++nf)
            #pragma unroll
            for (int r = 0; r < 4; ++r) {
                int o = mf * 16 + q * 4 + r;
                int n = nt * 128 + w * 32 + nf * 16 + l15;
                float v = acc[mf][nf][r] + bias[o];
                float u = v * v;
                float p = v * fmaf(0.0713548162f, u, 1.5957691216f);
                float e = __expf(-p);
                float g = v * __builtin_amdgcn_rcpf(1.f + e);
                out[((size_t)(b * 128 + o)) * NN + n] = g;
            }
}

extern "C" void kernel_launch(void* const* d_in, const int* in_sizes, int n_in,
                              void* d_out, int out_size, void* d_ws, size_t ws_size,
                              hipStream_t stream) {
    const float* x    = (const float*)d_in[0];  // [16][128][8192]
    const float* wsp  = (const float*)d_in[1];  // [128][128][64][2]
    const float* wc   = (const float*)d_in[2];  // [128][128]
    const float* bc   = (const float*)d_in[3];  // [128]
    float* out = (float*)d_out;

    unsigned short* T   = (unsigned short*)d_ws;            // 2 MB
    unsigned short* Tt  = T + (size_t)1048576;              // 2 MB
    unsigned short* Wcb = Tt + (size_t)1048576;             // 32 KB
    unsigned short* Asp = Wcb + 16384;                      // 512 KB
    unsigned short* Wpk = Asp + 262144;                     // 16.8 MB
    float* Cpart = (float*)(Wpk + (size_t)8388608);         // 16 MB
    float* Xf    = Cpart + (size_t)16 * 262144;             // 1 MB  (total ~38.3 MB)

    k_prep  <<<240,  256, 0, stream>>>(wc, wsp, T, Tt, Wcb, Wpk);
    k_dftmm <<<512,  256, 0, stream>>>(x, T, Cpart);
    k_reduce<<<1024, 256, 0, stream>>>(Cpart, Xf);
    k_mixmm <<<256,  64,  0, stream>>>(Xf, Wpk, Asp);
    k_out   <<<1024, 256, 0, stream>>>(x, Tt, Asp, Wcb, bc, out);
}